// Round 19
// baseline (584.238 us; speedup 1.0000x reference)
//
#include <hip/hip_runtime.h>
#include <hip/hip_bf16.h>

// R19: (1) GRU hs writes batched via 8-slot LDS history ring -> per-step
// barrier has no outstanding vm ops (kills the per-step vmcnt(0) drain);
// flush+drain once per 8 steps. (2) Embedding fused into GRU prologue.
// (3) MLP: 1024 WGs x 512 thr x 64 rows, launch_bounds(512,4) -> 2 WGs/CU
// for cross-WG latency hiding.

typedef __bf16 bf16_t;
typedef __bf16 bf16x8 __attribute__((ext_vector_type(8)));
typedef float f32x4 __attribute__((ext_vector_type(4)));

#define MFMA16(a, b, c) __builtin_amdgcn_mfma_f32_16x16x32_bf16(a, b, c, 0, 0, 0)

#define EMB 256
#define TSTEPS 128
#define OUTD 64

#define HS_OFF   0u           // bf16 65536x256 = 33,554,432
#define WHH_OFF  33554432u    // bf16 768x256  = 393,216
#define W1_OFF   33947648u    // bf16 512x256  = 262,144
#define W2_OFF   34209792u    // bf16 512x512  = 524,288
#define W3_OFF   34734080u    // bf16 512x512  = 524,288
#define MUW_OFF  35258368u    // bf16 64x512   = 65,536

__device__ __forceinline__ float rcpf(float x){ return __builtin_amdgcn_rcpf(x); }

// ---------------------------------------------------------------------------
__global__ __launch_bounds__(256) void convert_kernel(
    const float* __restrict__ whh, const float* __restrict__ w1,
    const float* __restrict__ w2, const float* __restrict__ w3,
    const float* __restrict__ muw, char* __restrict__ ws)
{
  const int g = blockIdx.x * 256 + threadIdx.x;
  const int G = gridDim.x * 256;
  bf16_t* d;
  d = (bf16_t*)(ws + WHH_OFF); for (int i = g; i < 196608; i += G) d[i] = (bf16_t)whh[i];
  d = (bf16_t*)(ws + W1_OFF);  for (int i = g; i < 131072; i += G) d[i] = (bf16_t)w1[i];
  d = (bf16_t*)(ws + W2_OFF);  for (int i = g; i < 262144; i += G) d[i] = (bf16_t)w2[i];
  d = (bf16_t*)(ws + W3_OFF);  for (int i = g; i < 262144; i += G) d[i] = (bf16_t)w3[i];
  d = (bf16_t*)(ws + MUW_OFF); for (int i = g; i < 32768;  i += G) d[i] = (bf16_t)muw[i];
}

// ---------------------------------------------------------------------------
// GRU: 32 WGs x 512 thr (8 waves), 16 rows/WG (= one batch b), 1 barrier/step.
// Embedding fused in prologue. h history in an 8-slot LDS ring; hs flushed
// every 8 steps (per-step barriers carry no vm ops). Wave wv owns h-cols
// [wv*32,+32) for all 3 gates; gates fully in-register.
// LDS: ring 67,584 + z 8,448 + h0 16,640 = 92,672 B.
// ---------------------------------------------------------------------------
__global__ __launch_bounds__(512) void gru_kernel(
    const float* __restrict__ z_t, const float* __restrict__ z_g,
    const float* __restrict__ w_emb, const bf16_t* __restrict__ w_hh,
    const float* __restrict__ b_ih, const float* __restrict__ b_hh,
    bf16_t* __restrict__ hs)
{
  __shared__ __align__(16) bf16_t hh[8][16][264];
  __shared__ __align__(16) float  ztmp[16][132];
  __shared__ __align__(16) float  h0s[16][260];

  const int tid  = threadIdx.x;
  const int wv   = tid >> 6;
  const int lane = tid & 63;
  const int l15  = lane & 15;
  const int quad = lane >> 4;
  const int bw0  = blockIdx.x * 16;

  // register-resident W_hh B-fragments: tile ct = gate*2+cc,
  // n = gate*256 + wv*32 + cc*16 + l15, k = kk*32 + quad*8 + j
  bf16x8 wfrag[6][8];
#pragma unroll
  for (int ct = 0; ct < 6; ++ct) {
    const int n = (ct >> 1) * 256 + wv * 32 + (ct & 1) * 16 + l15;
#pragma unroll
    for (int kk = 0; kk < 8; ++kk)
      wfrag[ct][kk] = *reinterpret_cast<const bf16x8*>(w_hh + (size_t)n * 256 + kk * 32 + quad * 8);
  }

  float br[2], bz[2], bin[2], bhn[2];
#pragma unroll
  for (int cc = 0; cc < 2; ++cc) {
    const int c = wv * 32 + cc * 16 + l15;
    br[cc]  = b_ih[c]       + b_hh[c];
    bz[cc]  = b_ih[256 + c] + b_hh[256 + c];
    bin[cc] = b_ih[512 + c];
    bhn[cc] = b_hh[512 + c];
  }

  // ---- fused embedding ----
  for (int i = tid; i < 16 * 128; i += 512) {
    const int m = i >> 7, k = i & 127;
    ztmp[m][k] = (k < 64) ? z_t[(bw0 + m) * 64 + k]
                          : z_g[(bw0 >> 4) * 64 + (k - 64)];
  }
  __syncthreads();
  {
    const int m = tid >> 5;
#pragma unroll
    for (int j = 0; j < 8; ++j) {
      const int c = (tid & 31) + 32 * j;
      const float4* wp = reinterpret_cast<const float4*>(w_emb + (size_t)c * 128);
      float s = 0.f;
#pragma unroll
      for (int k4 = 0; k4 < 32; ++k4) {
        const float4 w = wp[k4];
        s += ztmp[m][k4 * 4 + 0] * w.x + ztmp[m][k4 * 4 + 1] * w.y
           + ztmp[m][k4 * 4 + 2] * w.z + ztmp[m][k4 * 4 + 3] * w.w;
      }
      h0s[m][c] = s;
      hh[0][m][c] = (bf16_t)s;
    }
  }
  __syncthreads();

  // fp32 h master in registers: rows quad*4+r, cols wv*32+cc*16+l15
  float hm[4][2];
#pragma unroll
  for (int r = 0; r < 4; ++r)
#pragma unroll
    for (int cc = 0; cc < 2; ++cc)
      hm[r][cc] = h0s[quad * 4 + r][wv * 32 + cc * 16 + l15];

#pragma unroll 1
  for (int t = 0; t < TSTEPS; ++t) {
    const int rs = t & 7, wsl = (t + 1) & 7;

    // MFMA: gh tiles for owned cols
    f32x4 acc[6] = {};
#pragma unroll
    for (int kk = 0; kk < 8; ++kk) {
      bf16x8 a = *reinterpret_cast<const bf16x8*>(&hh[rs][l15][kk * 32 + quad * 8]);
#pragma unroll
      for (int ct = 0; ct < 6; ++ct)
        acc[ct] = MFMA16(a, wfrag[ct][kk], acc[ct]);
    }

    // gates in-register; write h_{t+1} to ring slot wsl
#pragma unroll
    for (int cc = 0; cc < 2; ++cc) {
      const int c = wv * 32 + cc * 16 + l15;
#pragma unroll
      for (int r = 0; r < 4; ++r) {
        const float gr = acc[cc][r]     + br[cc];
        const float gz = acc[2 + cc][r] + bz[cc];
        const float gn = acc[4 + cc][r] + bhn[cc];
        const float rr = rcpf(1.f + __expf(-gr));
        const float zz = rcpf(1.f + __expf(-gz));
        const float pre = bin[cc] + rr * gn;
        const float nn = 1.f - 2.f * rcpf(__expf(2.f * pre) + 1.f);
        hm[r][cc] = (1.f - zz) * nn + zz * hm[r][cc];
        hh[wsl][quad * 4 + r][c] = (bf16_t)hm[r][cc];
      }
    }
    __syncthreads();   // no outstanding vm ops on non-flush steps

    if ((t & 7) == 7) {
      // flush h_{t-6}..h_{t+1} (slots (j&7), j = t-6..t+1+... base+1..base+8)
      const int base = t - 7;
      const int m = tid >> 5, c0 = (tid & 31) * 8;
#pragma unroll
      for (int q = 0; q < 8; ++q) {
        const int j = base + 1 + q;        // state index (h_j -> hs[j-1])
        const int s = j & 7;
        bf16x8 v = *reinterpret_cast<const bf16x8*>(&hh[s][m][c0]);
        *reinterpret_cast<bf16x8*>(hs + ((size_t)(bw0 + m) * TSTEPS + (j - 1)) * EMB + c0) = v;
      }
      __syncthreads();   // protect ring slots from next step's writes
    }
  }
}

// ---------------------------------------------------------------------------
// Fused MLP: 1024 WGs x 512 thr (8 waves), 64 rows/WG, 2 WGs/CU.
// Wave wv owns cols [wv*64,+64) (4 col-tiles) x 4 m-tiles.
// ---------------------------------------------------------------------------
template<int KC>
__device__ __forceinline__ void mlp_layer(
    const bf16_t* __restrict__ W, const float* __restrict__ bias,
    bf16_t (*act)[520], int wv, int l15, int quad)
{
  f32x4 acc[4][4] = {};
#pragma unroll 1
  for (int kc = 0; kc < KC; ++kc) {
#pragma unroll
    for (int kk = 0; kk < 4; ++kk) {
      bf16x8 wf[4];
#pragma unroll
      for (int ct = 0; ct < 4; ++ct)
        wf[ct] = *reinterpret_cast<const bf16x8*>(
            W + (size_t)(wv * 64 + ct * 16 + l15) * (KC * 128) + kc * 128 + kk * 32 + quad * 8);
#pragma unroll
      for (int mt = 0; mt < 4; ++mt) {
        bf16x8 a = *reinterpret_cast<const bf16x8*>(&act[mt * 16 + l15][kc * 128 + kk * 32 + quad * 8]);
#pragma unroll
        for (int ct = 0; ct < 4; ++ct)
          acc[ct][mt] = MFMA16(a, wf[ct], acc[ct][mt]);
      }
    }
  }
  __syncthreads();
#pragma unroll
  for (int ct = 0; ct < 4; ++ct) {
    const int n = wv * 64 + ct * 16 + l15;
    const float b = bias[n];
#pragma unroll
    for (int mt = 0; mt < 4; ++mt)
#pragma unroll
      for (int r = 0; r < 4; ++r) {
        float x = acc[ct][mt][r] + b;
        x = (x > 0.f) ? x : (__expf(x) - 1.f);   // ELU
        act[mt * 16 + quad * 4 + r][n] = (bf16_t)x;
      }
  }
  __syncthreads();
}

__global__ __launch_bounds__(512, 4) void mlp_kernel(
    const bf16_t* __restrict__ hs,
    const bf16_t* __restrict__ w1, const float* __restrict__ b1,
    const bf16_t* __restrict__ w2, const float* __restrict__ b2,
    const bf16_t* __restrict__ w3, const float* __restrict__ b3,
    const bf16_t* __restrict__ muw, const float* __restrict__ mub,
    float* __restrict__ out)
{
  __shared__ __align__(16) bf16_t act[64][520];   // 66,560 B (x2 WGs/CU fits)

  const int tid  = threadIdx.x;
  const int wv   = tid >> 6;
  const int lane = tid & 63;
  const int l15  = lane & 15;
  const int quad = lane >> 4;
  const size_t r0 = (size_t)blockIdx.x * 64;

  for (int v = tid; v < 64 * 32; v += 512) {
    const int rr = v >> 5, cc = v & 31;
    bf16x8 x = *reinterpret_cast<const bf16x8*>(hs + (r0 + rr) * EMB + cc * 8);
    *reinterpret_cast<bf16x8*>(&act[rr][cc * 8]) = x;
  }
  __syncthreads();

  mlp_layer<2>(w1, b1, act, wv, l15, quad);   // 256 -> 512
  mlp_layer<4>(w2, b2, act, wv, l15, quad);   // 512 -> 512
  mlp_layer<4>(w3, b3, act, wv, l15, quad);   // 512 -> 512

  // mu head: wave wv -> col-tile (wv&3) of 64 cols, m-tiles (wv>>2)*2..+2
  f32x4 macc[2] = {};
  const int n   = (wv & 3) * 16 + l15;
  const int mtb = (wv >> 2) * 2;
#pragma unroll 1
  for (int kc = 0; kc < 4; ++kc) {
#pragma unroll
    for (int kk = 0; kk < 4; ++kk) {
      bf16x8 wf = *reinterpret_cast<const bf16x8*>(
          muw + (size_t)n * 512 + kc * 128 + kk * 32 + quad * 8);
#pragma unroll
      for (int i = 0; i < 2; ++i) {
        bf16x8 a = *reinterpret_cast<const bf16x8*>(
            &act[(mtb + i) * 16 + l15][kc * 128 + kk * 32 + quad * 8]);
        macc[i] = MFMA16(a, wf, macc[i]);
      }
    }
  }
  const float mb = mub[n];
#pragma unroll
  for (int i = 0; i < 2; ++i)
#pragma unroll
    for (int r = 0; r < 4; ++r)
      out[(r0 + (mtb + i) * 16 + quad * 4 + r) * OUTD + n] = macc[i][r] + mb;
}

// ---------------------------------------------------------------------------
extern "C" void kernel_launch(void* const* d_in, const int* in_sizes, int n_in,
                              void* d_out, int out_size, void* d_ws, size_t ws_size,
                              hipStream_t stream) {
  char* ws = (char*)d_ws;

  convert_kernel<<<256, 256, 0, stream>>>(
      (const float*)d_in[3], (const float*)d_in[6], (const float*)d_in[8],
      (const float*)d_in[10], (const float*)d_in[12], ws);

  gru_kernel<<<32, 512, 0, stream>>>(
      (const float*)d_in[0], (const float*)d_in[1], (const float*)d_in[2],
      (const bf16_t*)(ws + WHH_OFF),
      (const float*)d_in[4], (const float*)d_in[5],
      (bf16_t*)(ws + HS_OFF));

  mlp_kernel<<<1024, 512, 0, stream>>>(
      (const bf16_t*)(ws + HS_OFF),
      (const bf16_t*)(ws + W1_OFF), (const float*)d_in[7],
      (const bf16_t*)(ws + W2_OFF), (const float*)d_in[9],
      (const bf16_t*)(ws + W3_OFF), (const float*)d_in[11],
      (const bf16_t*)(ws + MUW_OFF), (const float*)d_in[13],
      (float*)d_out);
}

// Round 20
// 427.807 us; speedup vs baseline: 1.3657x; 1.3657x over previous
//
#include <hip/hip_runtime.h>
#include <hip/hip_bf16.h>

// R20: revert R19 (both changes regressed). GRU = R18 structure + relaxed
// per-step barrier (s_waitcnt lgkmcnt(0) + s_barrier via asm -- skips the
// vmcnt(0) drain of the per-step hs store; nothing in-kernel reads hs).
// MLP = R18 traffic shape (512 WGs x 128 rows) but 1024 thr / 16 waves
// (4/SIMD) for 2x latency hiding on L2 weight loads.

typedef __bf16 bf16_t;
typedef __bf16 bf16x8 __attribute__((ext_vector_type(8)));
typedef float f32x4 __attribute__((ext_vector_type(4)));

#define MFMA16(a, b, c) __builtin_amdgcn_mfma_f32_16x16x32_bf16(a, b, c, 0, 0, 0)

#define EMB 256
#define TSTEPS 128
#define OUTD 64

#define HS_OFF   0u           // bf16 65536x256 = 33,554,432
#define H0_OFF   33554432u    // f32 512x256   = 524,288
#define WHH_OFF  34078720u    // bf16 768x256  = 393,216
#define W1_OFF   34471936u    // bf16 512x256  = 262,144
#define W2_OFF   34734080u    // bf16 512x512  = 524,288
#define W3_OFF   35258368u    // bf16 512x512  = 524,288
#define MUW_OFF  35782656u    // bf16 64x512   = 65,536

__device__ __forceinline__ float rcpf(float x){ return __builtin_amdgcn_rcpf(x); }

// barrier that waits LDS only (no vmcnt drain of in-flight global stores)
__device__ __forceinline__ void lds_barrier() {
  asm volatile("s_waitcnt lgkmcnt(0)\n\ts_barrier" ::: "memory");
}

// ---------------------------------------------------------------------------
__global__ __launch_bounds__(256) void convert_kernel(
    const float* __restrict__ whh, const float* __restrict__ w1,
    const float* __restrict__ w2, const float* __restrict__ w3,
    const float* __restrict__ muw, char* __restrict__ ws)
{
  const int g = blockIdx.x * 256 + threadIdx.x;
  const int G = gridDim.x * 256;
  bf16_t* d;
  d = (bf16_t*)(ws + WHH_OFF); for (int i = g; i < 196608; i += G) d[i] = (bf16_t)whh[i];
  d = (bf16_t*)(ws + W1_OFF);  for (int i = g; i < 131072; i += G) d[i] = (bf16_t)w1[i];
  d = (bf16_t*)(ws + W2_OFF);  for (int i = g; i < 262144; i += G) d[i] = (bf16_t)w2[i];
  d = (bf16_t*)(ws + W3_OFF);  for (int i = g; i < 262144; i += G) d[i] = (bf16_t)w3[i];
  d = (bf16_t*)(ws + MUW_OFF); for (int i = g; i < 32768;  i += G) d[i] = (bf16_t)muw[i];
}

// ---------------------------------------------------------------------------
__global__ __launch_bounds__(256) void emb_kernel(
    const float* __restrict__ z_t, const float* __restrict__ z_g,
    const float* __restrict__ w_emb, float* __restrict__ h0)
{
  __shared__ float zrow[128];
  const int bw = blockIdx.x, tid = threadIdx.x;
  if (tid < 128)
    zrow[tid] = (tid < 64) ? z_t[bw * 64 + tid] : z_g[(bw >> 4) * 64 + (tid - 64)];
  __syncthreads();
  const float4* wp = reinterpret_cast<const float4*>(w_emb + (size_t)tid * 128);
  float s = 0.f;
#pragma unroll
  for (int k4 = 0; k4 < 32; ++k4) {
    const float4 w = wp[k4];
    s += zrow[k4 * 4 + 0] * w.x + zrow[k4 * 4 + 1] * w.y
       + zrow[k4 * 4 + 2] * w.z + zrow[k4 * 4 + 3] * w.w;
  }
  h0[(size_t)bw * 256 + tid] = s;
}

// ---------------------------------------------------------------------------
// GRU: 32 WGs x 512 thr (8 waves), 16 rows/WG, 1 relaxed barrier/step.
// Wave wv owns h-cols [wv*32,+32) for all 3 gates; gates fully in-register.
// h16 double-buffered bf16 LDS. (R18 structure, proven 202 us.)
// ---------------------------------------------------------------------------
__global__ __launch_bounds__(512) void gru_kernel(
    const float* __restrict__ h0, const bf16_t* __restrict__ w_hh,
    const float* __restrict__ b_ih, const float* __restrict__ b_hh,
    bf16_t* __restrict__ hs)
{
  __shared__ __align__(16) bf16_t h16[2][16][264];

  const int tid  = threadIdx.x;
  const int wv   = tid >> 6;
  const int lane = tid & 63;
  const int l15  = lane & 15;
  const int quad = lane >> 4;
  const int bw0  = blockIdx.x * 16;

  bf16x8 wfrag[6][8];
#pragma unroll
  for (int ct = 0; ct < 6; ++ct) {
    const int n = (ct >> 1) * 256 + wv * 32 + (ct & 1) * 16 + l15;
#pragma unroll
    for (int kk = 0; kk < 8; ++kk)
      wfrag[ct][kk] = *reinterpret_cast<const bf16x8*>(w_hh + (size_t)n * 256 + kk * 32 + quad * 8);
  }

  float br[2], bz[2], bin[2], bhn[2];
#pragma unroll
  for (int cc = 0; cc < 2; ++cc) {
    const int c = wv * 32 + cc * 16 + l15;
    br[cc]  = b_ih[c]       + b_hh[c];
    bz[cc]  = b_ih[256 + c] + b_hh[256 + c];
    bin[cc] = b_ih[512 + c];
    bhn[cc] = b_hh[512 + c];
  }

  float hm[4][2];
#pragma unroll
  for (int r = 0; r < 4; ++r)
#pragma unroll
    for (int cc = 0; cc < 2; ++cc) {
      const int row = quad * 4 + r, c = wv * 32 + cc * 16 + l15;
      hm[r][cc] = h0[(size_t)(bw0 + row) * 256 + c];
      h16[0][row][c] = (bf16_t)hm[r][cc];
    }
  __syncthreads();

#pragma unroll 1
  for (int t = 0; t < TSTEPS; ++t) {
    const int cur = t & 1, nxt = cur ^ 1;

    if (t > 0) {   // hs[t-1]; store left in flight (no vmcnt drain at barrier)
      const int m = tid >> 5, c0 = (tid & 31) * 8;
      bf16x8 v = *reinterpret_cast<const bf16x8*>(&h16[cur][m][c0]);
      *reinterpret_cast<bf16x8*>(hs + ((size_t)(bw0 + m) * TSTEPS + (t - 1)) * EMB + c0) = v;
    }

    f32x4 acc[6] = {};
#pragma unroll
    for (int kk = 0; kk < 8; ++kk) {
      bf16x8 a = *reinterpret_cast<const bf16x8*>(&h16[cur][l15][kk * 32 + quad * 8]);
#pragma unroll
      for (int ct = 0; ct < 6; ++ct)
        acc[ct] = MFMA16(a, wfrag[ct][kk], acc[ct]);
    }

#pragma unroll
    for (int cc = 0; cc < 2; ++cc) {
      const int c = wv * 32 + cc * 16 + l15;
#pragma unroll
      for (int r = 0; r < 4; ++r) {
        const float gr = acc[cc][r]     + br[cc];
        const float gz = acc[2 + cc][r] + bz[cc];
        const float gn = acc[4 + cc][r] + bhn[cc];
        const float rr = rcpf(1.f + __expf(-gr));
        const float zz = rcpf(1.f + __expf(-gz));
        const float pre = bin[cc] + rr * gn;
        const float nn = 1.f - 2.f * rcpf(__expf(2.f * pre) + 1.f);
        hm[r][cc] = nn + zz * (hm[r][cc] - nn);
        h16[nxt][quad * 4 + r][c] = (bf16_t)hm[r][cc];
      }
    }
    lds_barrier();   // LDS-only wait; hs stores stay in flight
  }

  {  // final hs[127] = h_128 (slot 0 after 128 steps)
    const int m = tid >> 5, c0 = (tid & 31) * 8;
    bf16x8 v = *reinterpret_cast<const bf16x8*>(&h16[0][m][c0]);
    *reinterpret_cast<bf16x8*>(hs + ((size_t)(bw0 + m) * TSTEPS + 127) * EMB + c0) = v;
  }
}

// ---------------------------------------------------------------------------
// Fused MLP: 512 WGs x 1024 thr (16 waves, 4/SIMD), 128 rows/WG.
// Wave wv owns cols [wv*32,+32) (2 col-tiles) x 8 m-tiles. acc = 64 VGPRs.
// ---------------------------------------------------------------------------
template<int KC>
__device__ __forceinline__ void mlp_layer(
    const bf16_t* __restrict__ W, const float* __restrict__ bias,
    bf16_t (*act)[520], int wv, int l15, int quad)
{
  f32x4 acc[2][8] = {};
#pragma unroll 1
  for (int kc = 0; kc < KC; ++kc) {
#pragma unroll
    for (int kk = 0; kk < 4; ++kk) {
      bf16x8 wf[2];
#pragma unroll
      for (int ct = 0; ct < 2; ++ct)
        wf[ct] = *reinterpret_cast<const bf16x8*>(
            W + (size_t)(wv * 32 + ct * 16 + l15) * (KC * 128) + kc * 128 + kk * 32 + quad * 8);
#pragma unroll
      for (int mt = 0; mt < 8; ++mt) {
        bf16x8 a = *reinterpret_cast<const bf16x8*>(&act[mt * 16 + l15][kc * 128 + kk * 32 + quad * 8]);
#pragma unroll
        for (int ct = 0; ct < 2; ++ct)
          acc[ct][mt] = MFMA16(a, wf[ct], acc[ct][mt]);
      }
    }
  }
  __syncthreads();
#pragma unroll
  for (int ct = 0; ct < 2; ++ct) {
    const int n = wv * 32 + ct * 16 + l15;
    const float b = bias[n];
#pragma unroll
    for (int mt = 0; mt < 8; ++mt)
#pragma unroll
      for (int r = 0; r < 4; ++r) {
        float x = acc[ct][mt][r] + b;
        x = (x > 0.f) ? x : (__expf(x) - 1.f);   // ELU
        act[mt * 16 + quad * 4 + r][n] = (bf16_t)x;
      }
  }
  __syncthreads();
}

__global__ __launch_bounds__(1024, 4) void mlp_kernel(
    const bf16_t* __restrict__ hs,
    const bf16_t* __restrict__ w1, const float* __restrict__ b1,
    const bf16_t* __restrict__ w2, const float* __restrict__ b2,
    const bf16_t* __restrict__ w3, const float* __restrict__ b3,
    const bf16_t* __restrict__ muw, const float* __restrict__ mub,
    float* __restrict__ out)
{
  __shared__ __align__(16) bf16_t act[128][520];   // 133,120 B

  const int tid  = threadIdx.x;
  const int wv   = tid >> 6;       // 0..15
  const int lane = tid & 63;
  const int l15  = lane & 15;
  const int quad = lane >> 4;
  const size_t r0 = (size_t)blockIdx.x * 128;

  for (int v = tid; v < 128 * 32; v += 1024) {
    const int rr = v >> 5, cc = v & 31;
    bf16x8 x = *reinterpret_cast<const bf16x8*>(hs + (r0 + rr) * EMB + cc * 8);
    *reinterpret_cast<bf16x8*>(&act[rr][cc * 8]) = x;
  }
  __syncthreads();

  mlp_layer<2>(w1, b1, act, wv, l15, quad);   // 256 -> 512
  mlp_layer<4>(w2, b2, act, wv, l15, quad);   // 512 -> 512
  mlp_layer<4>(w3, b3, act, wv, l15, quad);   // 512 -> 512

  // mu head: wave wv -> col-tile (wv&3), m-tiles (wv>>2)*2..+2
  f32x4 macc[2] = {};
  const int n   = (wv & 3) * 16 + l15;
  const int mtb = (wv >> 2) * 2;
#pragma unroll 1
  for (int kc = 0; kc < 4; ++kc) {
#pragma unroll
    for (int kk = 0; kk < 4; ++kk) {
      bf16x8 wf = *reinterpret_cast<const bf16x8*>(
          muw + (size_t)n * 512 + kc * 128 + kk * 32 + quad * 8);
#pragma unroll
      for (int i = 0; i < 2; ++i) {
        bf16x8 a = *reinterpret_cast<const bf16x8*>(
            &act[(mtb + i) * 16 + l15][kc * 128 + kk * 32 + quad * 8]);
        macc[i] = MFMA16(a, wf, macc[i]);
      }
    }
  }
  const float mb = mub[n];
#pragma unroll
  for (int i = 0; i < 2; ++i)
#pragma unroll
    for (int r = 0; r < 4; ++r)
      out[(r0 + (mtb + i) * 16 + quad * 4 + r) * OUTD + n] = macc[i][r] + mb;
}

// ---------------------------------------------------------------------------
extern "C" void kernel_launch(void* const* d_in, const int* in_sizes, int n_in,
                              void* d_out, int out_size, void* d_ws, size_t ws_size,
                              hipStream_t stream) {
  char* ws = (char*)d_ws;

  convert_kernel<<<256, 256, 0, stream>>>(
      (const float*)d_in[3], (const float*)d_in[6], (const float*)d_in[8],
      (const float*)d_in[10], (const float*)d_in[12], ws);

  emb_kernel<<<512, 256, 0, stream>>>(
      (const float*)d_in[0], (const float*)d_in[1], (const float*)d_in[2],
      (float*)(ws + H0_OFF));

  gru_kernel<<<32, 512, 0, stream>>>(
      (const float*)(ws + H0_OFF), (const bf16_t*)(ws + WHH_OFF),
      (const float*)d_in[4], (const float*)d_in[5],
      (bf16_t*)(ws + HS_OFF));

  mlp_kernel<<<512, 1024, 0, stream>>>(
      (const bf16_t*)(ws + HS_OFF),
      (const bf16_t*)(ws + W1_OFF), (const float*)d_in[7],
      (const bf16_t*)(ws + W2_OFF), (const float*)d_in[9],
      (const bf16_t*)(ws + W3_OFF), (const float*)d_in[11],
      (const bf16_t*)(ws + MUW_OFF), (const float*)d_in[13],
      (float*)d_out);
}

// Round 21
// 409.052 us; speedup vs baseline: 1.4283x; 1.0458x over previous
//
#include <hip/hip_runtime.h>
#include <hip/hip_bf16.h>

// R21: (1) GRU wave-skew: even waves s_setprio(1) during MFMA issue so their
// accs complete first and their gate-VALU overlaps odd waves' MFMA execution
// (breaks the phase-lock that serializes matrix and VALU pipes). hs store
// moved after MFMA issue. (2) MLP: R18's winning shape (512x512, 128 rows)
// with the k-fragment loop fully unrolled for deep load-ahead pipelining.

typedef __bf16 bf16_t;
typedef __bf16 bf16x8 __attribute__((ext_vector_type(8)));
typedef float f32x4 __attribute__((ext_vector_type(4)));

#define MFMA16(a, b, c) __builtin_amdgcn_mfma_f32_16x16x32_bf16(a, b, c, 0, 0, 0)

#define EMB 256
#define TSTEPS 128
#define OUTD 64

#define HS_OFF   0u           // bf16 65536x256 = 33,554,432
#define H0_OFF   33554432u    // f32 512x256   = 524,288
#define WHH_OFF  34078720u    // bf16 768x256  = 393,216
#define W1_OFF   34471936u    // bf16 512x256  = 262,144
#define W2_OFF   34734080u    // bf16 512x512  = 524,288
#define W3_OFF   35258368u    // bf16 512x512  = 524,288
#define MUW_OFF  35782656u    // bf16 64x512   = 65,536

__device__ __forceinline__ float rcpf(float x){ return __builtin_amdgcn_rcpf(x); }

__device__ __forceinline__ void lds_barrier() {
  asm volatile("s_waitcnt lgkmcnt(0)\n\ts_barrier" ::: "memory");
}

// ---------------------------------------------------------------------------
__global__ __launch_bounds__(256) void convert_kernel(
    const float* __restrict__ whh, const float* __restrict__ w1,
    const float* __restrict__ w2, const float* __restrict__ w3,
    const float* __restrict__ muw, char* __restrict__ ws)
{
  const int g = blockIdx.x * 256 + threadIdx.x;
  const int G = gridDim.x * 256;
  bf16_t* d;
  d = (bf16_t*)(ws + WHH_OFF); for (int i = g; i < 196608; i += G) d[i] = (bf16_t)whh[i];
  d = (bf16_t*)(ws + W1_OFF);  for (int i = g; i < 131072; i += G) d[i] = (bf16_t)w1[i];
  d = (bf16_t*)(ws + W2_OFF);  for (int i = g; i < 262144; i += G) d[i] = (bf16_t)w2[i];
  d = (bf16_t*)(ws + W3_OFF);  for (int i = g; i < 262144; i += G) d[i] = (bf16_t)w3[i];
  d = (bf16_t*)(ws + MUW_OFF); for (int i = g; i < 32768;  i += G) d[i] = (bf16_t)muw[i];
}

// ---------------------------------------------------------------------------
__global__ __launch_bounds__(256) void emb_kernel(
    const float* __restrict__ z_t, const float* __restrict__ z_g,
    const float* __restrict__ w_emb, float* __restrict__ h0)
{
  __shared__ float zrow[128];
  const int bw = blockIdx.x, tid = threadIdx.x;
  if (tid < 128)
    zrow[tid] = (tid < 64) ? z_t[bw * 64 + tid] : z_g[(bw >> 4) * 64 + (tid - 64)];
  __syncthreads();
  const float4* wp = reinterpret_cast<const float4*>(w_emb + (size_t)tid * 128);
  float s = 0.f;
#pragma unroll
  for (int k4 = 0; k4 < 32; ++k4) {
    const float4 w = wp[k4];
    s += zrow[k4 * 4 + 0] * w.x + zrow[k4 * 4 + 1] * w.y
       + zrow[k4 * 4 + 2] * w.z + zrow[k4 * 4 + 3] * w.w;
  }
  h0[(size_t)bw * 256 + tid] = s;
}

// ---------------------------------------------------------------------------
// GRU: 32 WGs x 512 thr (8 waves), 16 rows/WG, 1 relaxed barrier/step.
// Wave wv owns h-cols [wv*32,+32) for all 3 gates; gates fully in-register.
// Even waves prio-boosted during MFMA issue (wave-skew overlap).
// ---------------------------------------------------------------------------
__global__ __launch_bounds__(512) void gru_kernel(
    const float* __restrict__ h0, const bf16_t* __restrict__ w_hh,
    const float* __restrict__ b_ih, const float* __restrict__ b_hh,
    bf16_t* __restrict__ hs)
{
  __shared__ __align__(16) bf16_t h16[2][16][264];

  const int tid  = threadIdx.x;
  const int wv   = tid >> 6;
  const int lane = tid & 63;
  const int l15  = lane & 15;
  const int quad = lane >> 4;
  const int bw0  = blockIdx.x * 16;

  bf16x8 wfrag[6][8];
#pragma unroll
  for (int ct = 0; ct < 6; ++ct) {
    const int n = (ct >> 1) * 256 + wv * 32 + (ct & 1) * 16 + l15;
#pragma unroll
    for (int kk = 0; kk < 8; ++kk)
      wfrag[ct][kk] = *reinterpret_cast<const bf16x8*>(w_hh + (size_t)n * 256 + kk * 32 + quad * 8);
  }

  float br[2], bz[2], bin[2], bhn[2];
#pragma unroll
  for (int cc = 0; cc < 2; ++cc) {
    const int c = wv * 32 + cc * 16 + l15;
    br[cc]  = b_ih[c]       + b_hh[c];
    bz[cc]  = b_ih[256 + c] + b_hh[256 + c];
    bin[cc] = b_ih[512 + c];
    bhn[cc] = b_hh[512 + c];
  }

  float hm[4][2];
#pragma unroll
  for (int r = 0; r < 4; ++r)
#pragma unroll
    for (int cc = 0; cc < 2; ++cc) {
      const int row = quad * 4 + r, c = wv * 32 + cc * 16 + l15;
      hm[r][cc] = h0[(size_t)(bw0 + row) * 256 + c];
      h16[0][row][c] = (bf16_t)hm[r][cc];
    }
  __syncthreads();

  const bool hiprio = ((wv & 1) == 0);

#pragma unroll 1
  for (int t = 0; t < TSTEPS; ++t) {
    const int cur = t & 1, nxt = cur ^ 1;

    if (hiprio) asm volatile("s_setprio 1");
    f32x4 acc[6] = {};
#pragma unroll
    for (int kk = 0; kk < 8; ++kk) {
      bf16x8 a = *reinterpret_cast<const bf16x8*>(&h16[cur][l15][kk * 32 + quad * 8]);
#pragma unroll
      for (int ct = 0; ct < 6; ++ct)
        acc[ct] = MFMA16(a, wfrag[ct][kk], acc[ct]);
    }
    if (hiprio) asm volatile("s_setprio 0");

    if (t > 0) {   // issued while MFMAs execute; store left in flight
      const int m = tid >> 5, c0 = (tid & 31) * 8;
      bf16x8 v = *reinterpret_cast<const bf16x8*>(&h16[cur][m][c0]);
      *reinterpret_cast<bf16x8*>(hs + ((size_t)(bw0 + m) * TSTEPS + (t - 1)) * EMB + c0) = v;
    }

#pragma unroll
    for (int cc = 0; cc < 2; ++cc) {
      const int c = wv * 32 + cc * 16 + l15;
#pragma unroll
      for (int r = 0; r < 4; ++r) {
        const float gr = acc[cc][r]     + br[cc];
        const float gz = acc[2 + cc][r] + bz[cc];
        const float gn = acc[4 + cc][r] + bhn[cc];
        const float rr = rcpf(1.f + __expf(-gr));
        const float zz = rcpf(1.f + __expf(-gz));
        const float pre = bin[cc] + rr * gn;
        const float nn = 1.f - 2.f * rcpf(__expf(2.f * pre) + 1.f);
        hm[r][cc] = nn + zz * (hm[r][cc] - nn);
        h16[nxt][quad * 4 + r][c] = (bf16_t)hm[r][cc];
      }
    }
    lds_barrier();
  }

  {  // final hs[127]
    const int m = tid >> 5, c0 = (tid & 31) * 8;
    bf16x8 v = *reinterpret_cast<const bf16x8*>(&h16[0][m][c0]);
    *reinterpret_cast<bf16x8*>(hs + ((size_t)(bw0 + m) * TSTEPS + 127) * EMB + c0) = v;
  }
}

// ---------------------------------------------------------------------------
// Fused MLP: 512 WGs x 512 thr (8 waves), 128 rows/WG (R18 shape).
// Wave wv owns cols [wv*64,+64) (4 ct) x 8 m-tiles. k-fragment loop fully
// unrolled so the compiler hoists weight loads several frags ahead.
// ---------------------------------------------------------------------------
template<int KC>
__device__ __forceinline__ void mlp_layer(
    const bf16_t* __restrict__ W, const float* __restrict__ bias,
    bf16_t (*act)[520], int wv, int l15, int quad)
{
  f32x4 acc[4][8] = {};
  const size_t wstride = KC * 128;
  const bf16_t* wbase = W + (size_t)(wv * 64 + l15) * wstride + quad * 8;
#pragma unroll
  for (int f = 0; f < KC * 4; ++f) {
    bf16x8 wf[4];
#pragma unroll
    for (int ct = 0; ct < 4; ++ct)
      wf[ct] = *reinterpret_cast<const bf16x8*>(wbase + (size_t)ct * 16 * wstride + f * 32);
#pragma unroll
    for (int mt = 0; mt < 8; ++mt) {
      bf16x8 a = *reinterpret_cast<const bf16x8*>(&act[mt * 16 + l15][f * 32 + quad * 8]);
#pragma unroll
      for (int ct = 0; ct < 4; ++ct)
        acc[ct][mt] = MFMA16(a, wf[ct], acc[ct][mt]);
    }
  }
  __syncthreads();
#pragma unroll
  for (int ct = 0; ct < 4; ++ct) {
    const int n = wv * 64 + ct * 16 + l15;
    const float b = bias[n];
#pragma unroll
    for (int mt = 0; mt < 8; ++mt)
#pragma unroll
      for (int r = 0; r < 4; ++r) {
        float x = acc[ct][mt][r] + b;
        x = (x > 0.f) ? x : (__expf(x) - 1.f);   // ELU
        act[mt * 16 + quad * 4 + r][n] = (bf16_t)x;
      }
  }
  __syncthreads();
}

__global__ __launch_bounds__(512, 2) void mlp_kernel(
    const bf16_t* __restrict__ hs,
    const bf16_t* __restrict__ w1, const float* __restrict__ b1,
    const bf16_t* __restrict__ w2, const float* __restrict__ b2,
    const bf16_t* __restrict__ w3, const float* __restrict__ b3,
    const bf16_t* __restrict__ muw, const float* __restrict__ mub,
    float* __restrict__ out)
{
  __shared__ __align__(16) bf16_t act[128][520];   // 133,120 B

  const int tid  = threadIdx.x;
  const int wv   = tid >> 6;
  const int lane = tid & 63;
  const int l15  = lane & 15;
  const int quad = lane >> 4;
  const size_t r0 = (size_t)blockIdx.x * 128;

  for (int v = tid; v < 128 * 32; v += 512) {
    const int rr = v >> 5, cc = v & 31;
    bf16x8 x = *reinterpret_cast<const bf16x8*>(hs + (r0 + rr) * EMB + cc * 8);
    *reinterpret_cast<bf16x8*>(&act[rr][cc * 8]) = x;
  }
  __syncthreads();

  mlp_layer<2>(w1, b1, act, wv, l15, quad);   // 256 -> 512
  mlp_layer<4>(w2, b2, act, wv, l15, quad);   // 512 -> 512
  mlp_layer<4>(w3, b3, act, wv, l15, quad);   // 512 -> 512

  // mu head: wave wv -> col-tile (wv&3), m-tiles (wv>>2)*4 .. +4
  f32x4 macc[4] = {};
  const int n   = (wv & 3) * 16 + l15;
  const int mtb = (wv >> 2) * 4;
  const bf16_t* mwbase = muw + (size_t)n * 512 + quad * 8;
#pragma unroll
  for (int f = 0; f < 16; ++f) {
    bf16x8 wf = *reinterpret_cast<const bf16x8*>(mwbase + f * 32);
#pragma unroll
    for (int i = 0; i < 4; ++i) {
      bf16x8 a = *reinterpret_cast<const bf16x8*>(
          &act[(mtb + i) * 16 + l15][f * 32 + quad * 8]);
      macc[i] = MFMA16(a, wf, macc[i]);
    }
  }
  const float mb = mub[n];
#pragma unroll
  for (int i = 0; i < 4; ++i)
#pragma unroll
    for (int r = 0; r < 4; ++r)
      out[(r0 + (mtb + i) * 16 + quad * 4 + r) * OUTD + n] = macc[i][r] + mb;
}

// ---------------------------------------------------------------------------
extern "C" void kernel_launch(void* const* d_in, const int* in_sizes, int n_in,
                              void* d_out, int out_size, void* d_ws, size_t ws_size,
                              hipStream_t stream) {
  char* ws = (char*)d_ws;

  convert_kernel<<<256, 256, 0, stream>>>(
      (const float*)d_in[3], (const float*)d_in[6], (const float*)d_in[8],
      (const float*)d_in[10], (const float*)d_in[12], ws);

  emb_kernel<<<512, 256, 0, stream>>>(
      (const float*)d_in[0], (const float*)d_in[1], (const float*)d_in[2],
      (float*)(ws + H0_OFF));

  gru_kernel<<<32, 512, 0, stream>>>(
      (const float*)(ws + H0_OFF), (const bf16_t*)(ws + WHH_OFF),
      (const float*)d_in[4], (const float*)d_in[5],
      (bf16_t*)(ws + HS_OFF));

  mlp_kernel<<<512, 512, 0, stream>>>(
      (const bf16_t*)(ws + HS_OFF),
      (const bf16_t*)(ws + W1_OFF), (const float*)d_in[7],
      (const bf16_t*)(ws + W2_OFF), (const float*)d_in[9],
      (const bf16_t*)(ws + W3_OFF), (const float*)d_in[11],
      (const bf16_t*)(ws + MUW_OFF), (const float*)d_in[13],
      (float*)d_out);
}

// Round 22
// 390.881 us; speedup vs baseline: 1.4947x; 1.0465x over previous
//
#include <hip/hip_runtime.h>
#include <hip/hip_bf16.h>

// R22: GRU re-spread: 128 WGs x 4 rows/WG (gate-VALU is the bound and scales
// with rows/WG; MFMA count per WG is row-independent). Gates re-balanced via
// a small gh LDS scatter (quad==0 lanes hold all 4 real rows), 2 elems/thread.
// MLP reverted to R18's proven shape (512 WGs x 512 thr x 128 rows) with
// unroll(2) on the kc loop.

typedef __bf16 bf16_t;
typedef __bf16 bf16x2 __attribute__((ext_vector_type(2)));
typedef __bf16 bf16x8 __attribute__((ext_vector_type(8)));
typedef float f32x4 __attribute__((ext_vector_type(4)));

#define MFMA16(a, b, c) __builtin_amdgcn_mfma_f32_16x16x32_bf16(a, b, c, 0, 0, 0)

#define EMB 256
#define TSTEPS 128
#define OUTD 64

#define HS_OFF   0u           // bf16 65536x256 = 33,554,432
#define H0_OFF   33554432u    // f32 512x256   = 524,288
#define WHH_OFF  34078720u    // bf16 768x256  = 393,216
#define W1_OFF   34471936u    // bf16 512x256  = 262,144
#define W2_OFF   34734080u    // bf16 512x512  = 524,288
#define W3_OFF   35258368u    // bf16 512x512  = 524,288
#define MUW_OFF  35782656u    // bf16 64x512   = 65,536

__device__ __forceinline__ float rcpf(float x){ return __builtin_amdgcn_rcpf(x); }
__device__ __forceinline__ void lds_barrier() {
  asm volatile("s_waitcnt lgkmcnt(0)\n\ts_barrier" ::: "memory");
}

// ---------------------------------------------------------------------------
__global__ __launch_bounds__(256) void convert_kernel(
    const float* __restrict__ whh, const float* __restrict__ w1,
    const float* __restrict__ w2, const float* __restrict__ w3,
    const float* __restrict__ muw, char* __restrict__ ws)
{
  const int g = blockIdx.x * 256 + threadIdx.x;
  const int G = gridDim.x * 256;
  bf16_t* d;
  d = (bf16_t*)(ws + WHH_OFF); for (int i = g; i < 196608; i += G) d[i] = (bf16_t)whh[i];
  d = (bf16_t*)(ws + W1_OFF);  for (int i = g; i < 131072; i += G) d[i] = (bf16_t)w1[i];
  d = (bf16_t*)(ws + W2_OFF);  for (int i = g; i < 262144; i += G) d[i] = (bf16_t)w2[i];
  d = (bf16_t*)(ws + W3_OFF);  for (int i = g; i < 262144; i += G) d[i] = (bf16_t)w3[i];
  d = (bf16_t*)(ws + MUW_OFF); for (int i = g; i < 32768;  i += G) d[i] = (bf16_t)muw[i];
}

// ---------------------------------------------------------------------------
__global__ __launch_bounds__(256) void emb_kernel(
    const float* __restrict__ z_t, const float* __restrict__ z_g,
    const float* __restrict__ w_emb, float* __restrict__ h0)
{
  __shared__ float zrow[128];
  const int bw = blockIdx.x, tid = threadIdx.x;
  if (tid < 128)
    zrow[tid] = (tid < 64) ? z_t[bw * 64 + tid] : z_g[(bw >> 4) * 64 + (tid - 64)];
  __syncthreads();
  const float4* wp = reinterpret_cast<const float4*>(w_emb + (size_t)tid * 128);
  float s = 0.f;
#pragma unroll
  for (int k4 = 0; k4 < 32; ++k4) {
    const float4 w = wp[k4];
    s += zrow[k4 * 4 + 0] * w.x + zrow[k4 * 4 + 1] * w.y
       + zrow[k4 * 4 + 2] * w.z + zrow[k4 * 4 + 3] * w.w;
  }
  h0[(size_t)bw * 256 + tid] = s;
}

// ---------------------------------------------------------------------------
// GRU: 128 WGs x 512 thr (8 waves), 4 rows/WG. Wave wv owns gh cols
// [wv*96,+96) (6 tiles). Gate thread t owns (row=t>>7, cols (2t)&255,+1).
// 2 barriers/step; gate phase is 4x lighter than the 16-row variant.
// ---------------------------------------------------------------------------
__global__ __launch_bounds__(512) void gru_kernel(
    const float* __restrict__ h0, const bf16_t* __restrict__ w_hh,
    const float* __restrict__ b_ih, const float* __restrict__ b_hh,
    bf16_t* __restrict__ hs)
{
  __shared__ __align__(16) float  gh[4][772];
  __shared__ __align__(16) bf16_t h16[16][264];

  const int tid  = threadIdx.x;
  const int wv   = tid >> 6;
  const int lane = tid & 63;
  const int l15  = lane & 15;
  const int quad = lane >> 4;
  const int bw0  = blockIdx.x * 4;

  // register-resident W_hh: wave wv covers cols wv*96 + ct*16, ct=0..5
  bf16x8 wfrag[6][8];
#pragma unroll
  for (int ct = 0; ct < 6; ++ct) {
    const int n = wv * 96 + ct * 16 + l15;
#pragma unroll
    for (int kk = 0; kk < 8; ++kk)
      wfrag[ct][kk] = *reinterpret_cast<const bf16x8*>(w_hh + (size_t)n * 256 + kk * 32 + quad * 8);
  }

  // gate thread mapping: row = tid>>7 (0..3), cols c0=(2*tid)&255, c0+1
  const int grow = tid >> 7;
  const int c0   = (tid * 2) & 255;
  float br[2], bz[2], bin[2], bhn[2], hm[2];
#pragma unroll
  for (int j = 0; j < 2; ++j) {
    const int c = c0 + j;
    br[j]  = b_ih[c]       + b_hh[c];
    bz[j]  = b_ih[256 + c] + b_hh[256 + c];
    bin[j] = b_ih[512 + c];
    bhn[j] = b_hh[512 + c];
    hm[j]  = h0[(size_t)(bw0 + grow) * 256 + c];
  }
  // init h16: rows 0..3 = h0 (bf16), rows 4..15 = 0 (A-frag padding)
  {
    bf16x2 v; v[0] = (bf16_t)hm[0]; v[1] = (bf16_t)hm[1];
    *reinterpret_cast<bf16x2*>(&h16[grow][c0]) = v;
    for (int i = tid; i < 12 * 132; i += 512) {
      const int rr = 4 + (i / 132), cc = (i % 132) * 2;
      *reinterpret_cast<bf16x2*>(&h16[rr][cc]) = bf16x2{(bf16_t)0.f, (bf16_t)0.f};
    }
  }
  __syncthreads();

#pragma unroll 1
  for (int t = 0; t < TSTEPS; ++t) {
    // MFMA: gh = h @ W_hh^T (rows 4..15 of A are zero padding)
    f32x4 acc[6] = {};
#pragma unroll
    for (int kk = 0; kk < 8; ++kk) {
      bf16x8 a = *reinterpret_cast<const bf16x8*>(&h16[l15][kk * 32 + quad * 8]);
#pragma unroll
      for (int ct = 0; ct < 6; ++ct)
        acc[ct] = MFMA16(a, wfrag[ct][kk], acc[ct]);
    }
    // scatter real rows (quad==0 -> rows r=0..3) to gh
    if (quad == 0) {
#pragma unroll
      for (int ct = 0; ct < 6; ++ct) {
        const int n = wv * 96 + ct * 16 + l15;
#pragma unroll
        for (int r = 0; r < 4; ++r) gh[r][n] = acc[ct][r];
      }
    }
    lds_barrier();   // MFMA h16-reads + gh scatter complete

    // gates: 2 elems/thread
    bf16_t nh[2];
#pragma unroll
    for (int j = 0; j < 2; ++j) {
      const int c = c0 + j;
      const float gr = gh[grow][c]       + br[j];
      const float gz = gh[grow][256 + c] + bz[j];
      const float gn = gh[grow][512 + c] + bhn[j];
      const float rr = rcpf(1.f + __expf(-gr));
      const float zz = rcpf(1.f + __expf(-gz));
      const float pre = bin[j] + rr * gn;
      const float nn = 1.f - 2.f * rcpf(__expf(2.f * pre) + 1.f);
      hm[j] = nn + zz * (hm[j] - nn);
      nh[j] = (bf16_t)hm[j];
    }
    {
      bf16x2 v; v[0] = nh[0]; v[1] = nh[1];
      *reinterpret_cast<bf16x2*>(&h16[grow][c0]) = v;
      *reinterpret_cast<bf16x2*>(hs + ((size_t)(bw0 + grow) * TSTEPS + t) * EMB + c0) = v;
    }
    lds_barrier();   // h16 published (hs store left in flight)
  }
}

// ---------------------------------------------------------------------------
// Fused MLP: 512 WGs x 512 thr (8 waves), 128 rows/WG (R18 proven shape).
// Wave wv owns cols [wv*64,+64) (4 ct) x 8 m-tiles.
// ---------------------------------------------------------------------------
template<int KC>
__device__ __forceinline__ void mlp_layer(
    const bf16_t* __restrict__ W, const float* __restrict__ bias,
    bf16_t (*act)[520], int wv, int l15, int quad)
{
  f32x4 acc[4][8] = {};
#pragma unroll 2
  for (int kc = 0; kc < KC; ++kc) {
#pragma unroll
    for (int kk = 0; kk < 4; ++kk) {
      bf16x8 wf[4];
#pragma unroll
      for (int ct = 0; ct < 4; ++ct)
        wf[ct] = *reinterpret_cast<const bf16x8*>(
            W + (size_t)(wv * 64 + ct * 16 + l15) * (KC * 128) + kc * 128 + kk * 32 + quad * 8);
#pragma unroll
      for (int mt = 0; mt < 8; ++mt) {
        bf16x8 a = *reinterpret_cast<const bf16x8*>(&act[mt * 16 + l15][kc * 128 + kk * 32 + quad * 8]);
#pragma unroll
        for (int ct = 0; ct < 4; ++ct)
          acc[ct][mt] = MFMA16(a, wf[ct], acc[ct][mt]);
      }
    }
  }
  __syncthreads();
#pragma unroll
  for (int ct = 0; ct < 4; ++ct) {
    const int n = wv * 64 + ct * 16 + l15;
    const float b = bias[n];
#pragma unroll
    for (int mt = 0; mt < 8; ++mt)
#pragma unroll
      for (int r = 0; r < 4; ++r) {
        float x = acc[ct][mt][r] + b;
        x = (x > 0.f) ? x : (__expf(x) - 1.f);   // ELU
        act[mt * 16 + quad * 4 + r][n] = (bf16_t)x;
      }
  }
  __syncthreads();
}

__global__ __launch_bounds__(512, 2) void mlp_kernel(
    const bf16_t* __restrict__ hs,
    const bf16_t* __restrict__ w1, const float* __restrict__ b1,
    const bf16_t* __restrict__ w2, const float* __restrict__ b2,
    const bf16_t* __restrict__ w3, const float* __restrict__ b3,
    const bf16_t* __restrict__ muw, const float* __restrict__ mub,
    float* __restrict__ out)
{
  __shared__ __align__(16) bf16_t act[128][520];

  const int tid  = threadIdx.x;
  const int wv   = tid >> 6;
  const int lane = tid & 63;
  const int l15  = lane & 15;
  const int quad = lane >> 4;
  const size_t r0 = (size_t)blockIdx.x * 128;

  for (int v = tid; v < 128 * 32; v += 512) {
    const int rr = v >> 5, cc = v & 31;
    bf16x8 x = *reinterpret_cast<const bf16x8*>(hs + (r0 + rr) * EMB + cc * 8);
    *reinterpret_cast<bf16x8*>(&act[rr][cc * 8]) = x;
  }
  __syncthreads();

  mlp_layer<2>(w1, b1, act, wv, l15, quad);   // 256 -> 512
  mlp_layer<4>(w2, b2, act, wv, l15, quad);   // 512 -> 512
  mlp_layer<4>(w3, b3, act, wv, l15, quad);   // 512 -> 512

  // mu head: wave wv -> col-tile (wv&3), m-tiles (wv>>2)*4 .. +4
  f32x4 macc[4] = {};
  const int n   = (wv & 3) * 16 + l15;
  const int mtb = (wv >> 2) * 4;
#pragma unroll 1
  for (int kc = 0; kc < 4; ++kc) {
#pragma unroll
    for (int kk = 0; kk < 4; ++kk) {
      bf16x8 wf = *reinterpret_cast<const bf16x8*>(
          muw + (size_t)n * 512 + kc * 128 + kk * 32 + quad * 8);
#pragma unroll
      for (int i = 0; i < 4; ++i) {
        bf16x8 a = *reinterpret_cast<const bf16x8*>(
            &act[(mtb + i) * 16 + l15][kc * 128 + kk * 32 + quad * 8]);
        macc[i] = MFMA16(a, wf, macc[i]);
      }
    }
  }
  const float mb = mub[n];
#pragma unroll
  for (int i = 0; i < 4; ++i)
#pragma unroll
    for (int r = 0; r < 4; ++r)
      out[(r0 + (mtb + i) * 16 + quad * 4 + r) * OUTD + n] = macc[i][r] + mb;
}

// ---------------------------------------------------------------------------
extern "C" void kernel_launch(void* const* d_in, const int* in_sizes, int n_in,
                              void* d_out, int out_size, void* d_ws, size_t ws_size,
                              hipStream_t stream) {
  char* ws = (char*)d_ws;

  convert_kernel<<<256, 256, 0, stream>>>(
      (const float*)d_in[3], (const float*)d_in[6], (const float*)d_in[8],
      (const float*)d_in[10], (const float*)d_in[12], ws);

  emb_kernel<<<512, 256, 0, stream>>>(
      (const float*)d_in[0], (const float*)d_in[1], (const float*)d_in[2],
      (float*)(ws + H0_OFF));

  gru_kernel<<<128, 512, 0, stream>>>(
      (const float*)(ws + H0_OFF), (const bf16_t*)(ws + WHH_OFF),
      (const float*)d_in[4], (const float*)d_in[5],
      (bf16_t*)(ws + HS_OFF));

  mlp_kernel<<<512, 512, 0, stream>>>(
      (const bf16_t*)(ws + HS_OFF),
      (const bf16_t*)(ws + W1_OFF), (const float*)d_in[7],
      (const bf16_t*)(ws + W2_OFF), (const float*)d_in[9],
      (const bf16_t*)(ws + W3_OFF), (const float*)d_in[11],
      (const bf16_t*)(ws + MUW_OFF), (const float*)d_in[13],
      (float*)d_out);
}